// Round 1
// baseline (1743.893 us; speedup 1.0000x reference)
//
#include <hip/hip_runtime.h>
#include <hip/hip_bf16.h>

typedef unsigned short u16;
typedef unsigned int u32;

static const int DD = 768;
static const int SS = 2048;
static const int BB = 8;
static const int HH = 12;
static const int NBLK = 16;   // S / 128
static const int ROWS = BB * SS;          // 16384
static const size_t AD = (size_t)ROWS * DD;   // activation element count
static const size_t D2 = (size_t)DD * DD;
static const size_t DI = (size_t)DD * 3072;

typedef __attribute__((ext_vector_type(8))) short short8;
typedef __attribute__((ext_vector_type(4))) float f32x4;

union U16x8 { uint4 u; short8 s; };

__device__ __forceinline__ float bl(u32 u) { return __uint_as_float(u << 16); }
__device__ __forceinline__ float bh(u32 u) { return __uint_as_float(u & 0xffff0000u); }
__device__ __forceinline__ u16 f2b(float f) {
    u32 u = __float_as_uint(f);
    u += 0x7fffu + ((u >> 16) & 1u);
    return (u16)(u >> 16);
}
__device__ __forceinline__ u32 pack2(float lo, float hi) {
    return (u32)f2b(lo) | ((u32)f2b(hi) << 16);
}

// ---------------- elementwise f32 -> bf16 cast ----------------
__global__ __launch_bounds__(256) void cast_bf16(const float* __restrict__ x,
                                                 u16* __restrict__ xb, int n) {
    int i = (blockIdx.x * 256 + threadIdx.x) * 4;
    if (i < n) {
        float4 v = *reinterpret_cast<const float4*>(x + i);
        uint2 p;
        p.x = pack2(v.x, v.y);
        p.y = pack2(v.z, v.w);
        *reinterpret_cast<uint2*>(xb + i) = p;
    }
}

// ---------------- cast + transpose: W[K,N] f32 -> WT[N,K] bf16 ----------------
__global__ __launch_bounds__(256) void cast_transpose(const float* __restrict__ W,
                                                      u16* __restrict__ WT,
                                                      int K, int N) {
    __shared__ float tile[32][33];
    int bx = blockIdx.x;  // along N
    int by = blockIdx.y;  // along K
    int tx = threadIdx.x; // 0..31
    int ty = threadIdx.y; // 0..7
#pragma unroll
    for (int i = 0; i < 4; i++) {
        int kr = by * 32 + ty + i * 8;
        tile[ty + i * 8][tx] = W[(size_t)kr * N + bx * 32 + tx];
    }
    __syncthreads();
#pragma unroll
    for (int i = 0; i < 4; i++) {
        int nr = bx * 32 + ty + i * 8;
        WT[(size_t)nr * K + by * 32 + tx] = f2b(tile[tx][ty + i * 8]);
    }
}

// ---------------- GEMM: C[M,N] = A[M,K](bf16) @ BT[N,K](bf16)^T + bias ----------------
// EPI 0: bf16 out;  1: f32 out;  2: gelu -> bf16 out
template <int EPI>
__global__ __launch_bounds__(256) void gemm_bf16(const u16* __restrict__ A,
                                                 const u16* __restrict__ BT,
                                                 const float* __restrict__ bias,
                                                 void* __restrict__ Cout,
                                                 int M, int N, int K) {
    __shared__ uint4 As4[128 * 4];
    __shared__ uint4 Bs4[128 * 4];
    const int m0 = blockIdx.y * 128, n0 = blockIdx.x * 128;
    const int tid = threadIdx.x;
    const int lane = tid & 63, wid = tid >> 6;
    const int wr = wid >> 1, wc = wid & 1;
    const int lr = lane & 15, ls = lane >> 4;
    const int srow = tid >> 1, half = tid & 1;

    f32x4 acc[4][4];
#pragma unroll
    for (int i = 0; i < 4; i++)
#pragma unroll
        for (int j = 0; j < 4; j++) acc[i][j] = (f32x4){0.f, 0.f, 0.f, 0.f};

    const size_t aBase = (size_t)(m0 + srow) * K + half * 16;
    const size_t bBase = (size_t)(n0 + srow) * K + half * 16;
    const int sw0 = (2 * half + 0) ^ ((srow >> 1) & 3);
    const int sw1 = (2 * half + 1) ^ ((srow >> 1) & 3);

    for (int kt = 0; kt < K; kt += 32) {
        const uint4* pA = reinterpret_cast<const uint4*>(A + aBase + kt);
        const uint4* pB = reinterpret_cast<const uint4*>(BT + bBase + kt);
        uint4 a0 = pA[0], a1 = pA[1], b0 = pB[0], b1 = pB[1];
        __syncthreads();
        As4[srow * 4 + sw0] = a0;
        As4[srow * 4 + sw1] = a1;
        Bs4[srow * 4 + sw0] = b0;
        Bs4[srow * 4 + sw1] = b1;
        __syncthreads();
        U16x8 af[4], bf[4];
#pragma unroll
        for (int mi = 0; mi < 4; mi++) {
            int r = wr * 64 + mi * 16 + lr;
            af[mi].u = As4[r * 4 + (ls ^ ((r >> 1) & 3))];
        }
#pragma unroll
        for (int ni = 0; ni < 4; ni++) {
            int c = wc * 64 + ni * 16 + lr;
            bf[ni].u = Bs4[c * 4 + (ls ^ ((c >> 1) & 3))];
        }
#pragma unroll
        for (int mi = 0; mi < 4; mi++)
#pragma unroll
            for (int ni = 0; ni < 4; ni++)
                acc[mi][ni] = __builtin_amdgcn_mfma_f32_16x16x32_bf16(
                    af[mi].s, bf[ni].s, acc[mi][ni], 0, 0, 0);
    }

#pragma unroll
    for (int mi = 0; mi < 4; mi++) {
#pragma unroll
        for (int ni = 0; ni < 4; ni++) {
            int col = n0 + wc * 64 + ni * 16 + lr;
            float bs = bias[col];
#pragma unroll
            for (int r2 = 0; r2 < 4; r2++) {
                int row = m0 + wr * 64 + mi * 16 + ls * 4 + r2;
                float v = acc[mi][ni][r2] + bs;
                if (EPI == 2) v = 0.5f * v * (1.0f + erff(v * 0.70710678118654752f));
                if (EPI == 1)
                    ((float*)Cout)[(size_t)row * N + col] = v;
                else
                    ((u16*)Cout)[(size_t)row * N + col] = f2b(v);
            }
        }
    }
}

// ---------------- residual add + LayerNorm (writes f32 + bf16) ----------------
__global__ __launch_bounds__(256) void resid_ln(const float* __restrict__ a,
                                                const float* __restrict__ res,
                                                const float* __restrict__ g,
                                                const float* __restrict__ be,
                                                float* __restrict__ of,
                                                u16* __restrict__ ob) {
    __shared__ float red[8];
    const int row = blockIdx.x;
    const int tid = threadIdx.x;
    const size_t base = (size_t)row * 768;
    float v[3];
    float s = 0.f;
#pragma unroll
    for (int i = 0; i < 3; i++) {
        int c = tid + i * 256;
        v[i] = a[base + c] + res[base + c];
        s += v[i];
    }
#pragma unroll
    for (int off = 32; off; off >>= 1) s += __shfl_down(s, off);
    if ((tid & 63) == 0) red[tid >> 6] = s;
    __syncthreads();
    float mean = (red[0] + red[1] + red[2] + red[3]) * (1.f / 768.f);
    float q = 0.f;
#pragma unroll
    for (int i = 0; i < 3; i++) {
        float d = v[i] - mean;
        q += d * d;
    }
#pragma unroll
    for (int off = 32; off; off >>= 1) q += __shfl_down(q, off);
    if ((tid & 63) == 0) red[4 + (tid >> 6)] = q;
    __syncthreads();
    float var = (red[4] + red[5] + red[6] + red[7]) * (1.f / 768.f);
    float inv = rsqrtf(var + 1e-12f);
#pragma unroll
    for (int i = 0; i < 3; i++) {
        int c = tid + i * 256;
        float y = (v[i] - mean) * inv * g[c] + be[c];
        of[base + c] = y;
        ob[base + c] = f2b(y);
    }
}

// ---------------- halo block attention (flash-style, VALU) ----------------
__global__ __launch_bounds__(128) void attn_halo(const u16* __restrict__ Q,
                                                 const u16* __restrict__ Kx,
                                                 const u16* __restrict__ Vx,
                                                 u16* __restrict__ Ctx) {
    __shared__ uint4 Kl[192][8];
    __shared__ uint4 Vl[192][8];
    const int bid = blockIdx.x;
    const int h = bid % HH;
    const int n = (bid / HH) % NBLK;
    const int b = bid / (HH * NBLK);
    const int tid = threadIdx.x;

    for (int r = tid; r < 192; r += 128) {
        int t = n * 128 - 32 + r;
        if (t >= 0 && t < SS) {
            const uint4* pk = reinterpret_cast<const uint4*>(Kx + ((size_t)(b * SS + t)) * 768 + h * 64);
            const uint4* pv = reinterpret_cast<const uint4*>(Vx + ((size_t)(b * SS + t)) * 768 + h * 64);
#pragma unroll
            for (int i = 0; i < 8; i++) {
                Kl[r][i] = pk[i];
                Vl[r][i] = pv[i];
            }
        } else {
            uint4 z = {0, 0, 0, 0};
#pragma unroll
            for (int i = 0; i < 8; i++) {
                Kl[r][i] = z;
                Vl[r][i] = z;
            }
        }
    }
    __syncthreads();

    const size_t qrow = (size_t)(b * SS + n * 128 + tid);
    const uint4* qp = reinterpret_cast<const uint4*>(Q + qrow * 768 + h * 64);
    float q[64];
#pragma unroll
    for (int i = 0; i < 8; i++) {
        uint4 u = qp[i];
        q[8 * i + 0] = bl(u.x); q[8 * i + 1] = bh(u.x);
        q[8 * i + 2] = bl(u.y); q[8 * i + 3] = bh(u.y);
        q[8 * i + 4] = bl(u.z); q[8 * i + 5] = bh(u.z);
        q[8 * i + 6] = bl(u.w); q[8 * i + 7] = bh(u.w);
    }
    float o[64];
#pragma unroll
    for (int d = 0; d < 64; d++) o[d] = 0.f;
    float m = -1e30f, l = 0.f;
    const int lo_inv = (n == 0) ? 32 : 0;
    const int hi_val = (n == NBLK - 1) ? 160 : 192;

    for (int c = 0; c < 24; ++c) {
        float s[8];
        float cm = -1e30f;
#pragma unroll
        for (int jj = 0; jj < 8; jj++) {
            int j = c * 8 + jj;
            float a0 = 0.f;
#pragma unroll
            for (int i = 0; i < 8; i++) {
                uint4 kv = Kl[j][i];
                a0 += bl(kv.x) * q[8 * i + 0] + bh(kv.x) * q[8 * i + 1]
                    + bl(kv.y) * q[8 * i + 2] + bh(kv.y) * q[8 * i + 3]
                    + bl(kv.z) * q[8 * i + 4] + bh(kv.z) * q[8 * i + 5]
                    + bl(kv.w) * q[8 * i + 6] + bh(kv.w) * q[8 * i + 7];
            }
            a0 *= 0.125f;
            if (j < lo_inv || j >= hi_val) a0 = -3.0e38f;
            s[jj] = a0;
            cm = fmaxf(cm, a0);
        }
        float mn = fmaxf(m, cm);
        float sc = __expf(m - mn);
        l *= sc;
#pragma unroll
        for (int d = 0; d < 64; d++) o[d] *= sc;
#pragma unroll
        for (int jj = 0; jj < 8; jj++) {
            int j = c * 8 + jj;
            float w = __expf(s[jj] - mn);
            l += w;
#pragma unroll
            for (int i = 0; i < 8; i++) {
                uint4 vv = Vl[j][i];
                o[8 * i + 0] += w * bl(vv.x); o[8 * i + 1] += w * bh(vv.x);
                o[8 * i + 2] += w * bl(vv.y); o[8 * i + 3] += w * bh(vv.y);
                o[8 * i + 4] += w * bl(vv.z); o[8 * i + 5] += w * bh(vv.z);
                o[8 * i + 6] += w * bl(vv.w); o[8 * i + 7] += w * bh(vv.w);
            }
        }
        m = mn;
    }
    float inv = 1.f / l;
    u32* op = reinterpret_cast<u32*>(Ctx + qrow * 768 + h * 64);
#pragma unroll
    for (int i = 0; i < 32; i++) op[i] = pack2(o[2 * i] * inv, o[2 * i + 1] * inv);
}

extern "C" void kernel_launch(void* const* d_in, const int* in_sizes, int n_in,
                              void* d_out, int out_size, void* d_ws, size_t ws_size,
                              hipStream_t stream) {
    (void)in_sizes; (void)n_in; (void)out_size; (void)ws_size;
    const float* x    = (const float*)d_in[0];
    const float* Wq   = (const float*)d_in[1];
    const float* bq   = (const float*)d_in[2];
    const float* Wk   = (const float*)d_in[3];
    const float* bk   = (const float*)d_in[4];
    const float* Wv   = (const float*)d_in[5];
    const float* bv   = (const float*)d_in[6];
    const float* Wo   = (const float*)d_in[7];
    const float* bo   = (const float*)d_in[8];
    const float* ln1g = (const float*)d_in[9];
    const float* ln1b = (const float*)d_in[10];
    const float* W1   = (const float*)d_in[11];
    const float* b1   = (const float*)d_in[12];
    const float* W2   = (const float*)d_in[13];
    const float* b2   = (const float*)d_in[14];
    const float* ln2g = (const float*)d_in[15];
    const float* ln2b = (const float*)d_in[16];
    float* out = (float*)d_out;

    char* ws = (char*)d_ws;
    size_t off = 0;
    auto alloc = [&](size_t bytes) -> char* {
        char* p = ws + off;
        off += (bytes + 255) & ~(size_t)255;
        return p;
    };
    u16* WqT = (u16*)alloc(2 * D2 * sizeof(u16));
    u16* WkT = (u16*)alloc(2 * D2 * sizeof(u16));
    u16* WvT = (u16*)alloc(2 * D2 * sizeof(u16));
    u16* WoT = (u16*)alloc(2 * D2 * sizeof(u16));
    u16* W1T = (u16*)alloc(2 * DI * sizeof(u16));
    u16* W2T = (u16*)alloc(2 * DI * sizeof(u16));
    u16* Xb   = (u16*)alloc(AD * sizeof(u16));
    u16* RegA = (u16*)alloc(4 * AD * sizeof(u16)); // Qb,Kb,Vb,Ctxb; reused as H1b
    float* AttnF = (float*)alloc(AD * sizeof(float));
    u16*   AttnB = (u16*)alloc(AD * sizeof(u16));
    float* H2f   = (float*)alloc(AD * sizeof(float));
    u16* Qb = RegA;
    u16* Kb = RegA + AD;
    u16* Vb = RegA + 2 * AD;
    u16* Ctxb = RegA + 3 * AD;
    u16* H1b = RegA;

    // cast input x
    {
        int nelem = ROWS * DD;
        cast_bf16<<<dim3(nelem / 4 / 256), dim3(256), 0, stream>>>(x, Xb, nelem);
    }
    // cast+transpose all weights
    for (int l = 0; l < 2; l++) {
        cast_transpose<<<dim3(24, 24), dim3(32, 8), 0, stream>>>(Wq + l * D2, WqT + l * D2, 768, 768);
        cast_transpose<<<dim3(24, 24), dim3(32, 8), 0, stream>>>(Wk + l * D2, WkT + l * D2, 768, 768);
        cast_transpose<<<dim3(24, 24), dim3(32, 8), 0, stream>>>(Wv + l * D2, WvT + l * D2, 768, 768);
        cast_transpose<<<dim3(24, 24), dim3(32, 8), 0, stream>>>(Wo + l * D2, WoT + l * D2, 768, 768);
        cast_transpose<<<dim3(96, 24), dim3(32, 8), 0, stream>>>(W1 + l * DI, W1T + l * DI, 768, 3072);
        cast_transpose<<<dim3(24, 96), dim3(32, 8), 0, stream>>>(W2 + l * DI, W2T + l * DI, 3072, 768);
    }

    const float* xres = x;
    for (int l = 0; l < 2; l++) {
        gemm_bf16<0><<<dim3(6, 128), 256, 0, stream>>>(Xb, WqT + l * D2, bq + l * 768, Qb, ROWS, 768, 768);
        gemm_bf16<0><<<dim3(6, 128), 256, 0, stream>>>(Xb, WkT + l * D2, bk + l * 768, Kb, ROWS, 768, 768);
        gemm_bf16<0><<<dim3(6, 128), 256, 0, stream>>>(Xb, WvT + l * D2, bv + l * 768, Vb, ROWS, 768, 768);
        attn_halo<<<dim3(BB * NBLK * HH), 128, 0, stream>>>(Qb, Kb, Vb, Ctxb);
        gemm_bf16<1><<<dim3(6, 128), 256, 0, stream>>>(Ctxb, WoT + l * D2, bo + l * 768, H2f, ROWS, 768, 768);
        resid_ln<<<dim3(ROWS), 256, 0, stream>>>(H2f, xres, ln1g + l * 768, ln1b + l * 768, AttnF, AttnB);
        gemm_bf16<2><<<dim3(24, 128), 256, 0, stream>>>(AttnB, W1T + l * DI, b1 + l * 3072, H1b, ROWS, 3072, 768);
        gemm_bf16<1><<<dim3(6, 128), 256, 0, stream>>>(H1b, W2T + l * DI, b2 + l * 768, H2f, ROWS, 768, 3072);
        float* outl = out + (size_t)l * AD;
        resid_ln<<<dim3(ROWS), 256, 0, stream>>>(H2f, AttnF, ln2g + l * 768, ln2b + l * 768, outl, Xb);
        xres = outl;
    }
}

// Round 2
// 1029.514 us; speedup vs baseline: 1.6939x; 1.6939x over previous
//
#include <hip/hip_runtime.h>
#include <hip/hip_bf16.h>

typedef unsigned short u16;
typedef unsigned int u32;

static const int DD = 768;
static const int SS = 2048;
static const int BB = 8;
static const int HH = 12;
static const int NBLK = 16;   // S / 128
static const int ROWS = BB * SS;          // 16384
static const size_t AD = (size_t)ROWS * DD;   // activation element count
static const size_t D2 = (size_t)DD * DD;
static const size_t DI = (size_t)DD * 3072;

typedef __attribute__((ext_vector_type(8))) short short8;
typedef __attribute__((ext_vector_type(4))) float f32x4;

union U16x8 { uint4 u; short8 s; };

__device__ __forceinline__ float bl(u32 u) { return __uint_as_float(u << 16); }
__device__ __forceinline__ float bh(u32 u) { return __uint_as_float(u & 0xffff0000u); }
__device__ __forceinline__ u16 f2b(float f) {
    u32 u = __float_as_uint(f);
    u += 0x7fffu + ((u >> 16) & 1u);
    return (u16)(u >> 16);
}
__device__ __forceinline__ u32 pack2(float lo, float hi) {
    return (u32)f2b(lo) | ((u32)f2b(hi) << 16);
}

// async global->LDS, 16B per lane (dest must be wave-uniform base + lane*16)
__device__ __forceinline__ void gload16(const u16* g, u16* l) {
    __builtin_amdgcn_global_load_lds(
        (const __attribute__((address_space(1))) void*)g,
        (__attribute__((address_space(3))) void*)l, 16, 0, 0);
}

// ---------------- elementwise f32 -> bf16 cast ----------------
__global__ __launch_bounds__(256) void cast_bf16(const float* __restrict__ x,
                                                 u16* __restrict__ xb, int n) {
    int i = (blockIdx.x * 256 + threadIdx.x) * 4;
    if (i < n) {
        float4 v = *reinterpret_cast<const float4*>(x + i);
        uint2 p;
        p.x = pack2(v.x, v.y);
        p.y = pack2(v.z, v.w);
        *reinterpret_cast<uint2*>(xb + i) = p;
    }
}

// ---------------- cast + transpose: W[K,N] f32 -> WT[N,K] bf16 ----------------
__global__ __launch_bounds__(256) void cast_transpose(const float* __restrict__ W,
                                                      u16* __restrict__ WT,
                                                      int K, int N) {
    __shared__ float tile[32][33];
    int bx = blockIdx.x;  // along N
    int by = blockIdx.y;  // along K
    int tx = threadIdx.x; // 0..31
    int ty = threadIdx.y; // 0..7
#pragma unroll
    for (int i = 0; i < 4; i++) {
        int kr = by * 32 + ty + i * 8;
        tile[ty + i * 8][tx] = W[(size_t)kr * N + bx * 32 + tx];
    }
    __syncthreads();
#pragma unroll
    for (int i = 0; i < 4; i++) {
        int nr = bx * 32 + ty + i * 8;
        WT[(size_t)nr * K + by * 32 + tx] = f2b(tile[tx][ty + i * 8]);
    }
}

// ---------------- GEMM: C[M,N] = A[M,K](bf16) @ BT[N,K](bf16)^T + bias ----------------
// EPI 0: bf16 out; 1: f32 out; 2: gelu -> bf16 out; 3: transposed bf16 out C[col*M+row]
template <int EPI>
__global__ __launch_bounds__(256) void gemm_bf16(const u16* __restrict__ A,
                                                 const u16* __restrict__ BT,
                                                 const float* __restrict__ bias,
                                                 void* __restrict__ Cout,
                                                 int M, int N, int K) {
    __shared__ u16 As[128 * 32];
    __shared__ u16 Bs[128 * 32];
    const int m0 = blockIdx.y * 128, n0 = blockIdx.x * 128;
    const int tid = threadIdx.x;
    const int lane = tid & 63, wid = tid >> 6;
    const int wr = wid >> 1, wc = wid & 1;
    const int lr = lane & 15, ls = lane >> 4;

    f32x4 acc[4][4];
#pragma unroll
    for (int i = 0; i < 4; i++)
#pragma unroll
        for (int j = 0; j < 4; j++) acc[i][j] = (f32x4){0.f, 0.f, 0.f, 0.f};

    const int srow = tid >> 2, schunk = tid & 3;
    const u16* aS0 = A + (size_t)(m0 + srow) * K + schunk * 8;
    const u16* aS1 = A + (size_t)(m0 + 64 + srow) * K + schunk * 8;
    const u16* bS0 = BT + (size_t)(n0 + srow) * K + schunk * 8;
    const u16* bS1 = BT + (size_t)(n0 + 64 + srow) * K + schunk * 8;
    u16* aD0 = As + tid * 8;
    u16* aD1 = As + 2048 + tid * 8;
    u16* bD0 = Bs + tid * 8;
    u16* bD1 = Bs + 2048 + tid * 8;

    for (int kt = 0; kt < K; kt += 32) {
        __syncthreads();
        gload16(aS0 + kt, aD0);
        gload16(aS1 + kt, aD1);
        gload16(bS0 + kt, bD0);
        gload16(bS1 + kt, bD1);
        __syncthreads();
        U16x8 af[4], bfr[4];
#pragma unroll
        for (int mi = 0; mi < 4; mi++)
            af[mi].u = *(const uint4*)(As + (wr * 64 + mi * 16 + lr) * 32 + ls * 8);
#pragma unroll
        for (int ni = 0; ni < 4; ni++)
            bfr[ni].u = *(const uint4*)(Bs + (wc * 64 + ni * 16 + lr) * 32 + ls * 8);
#pragma unroll
        for (int mi = 0; mi < 4; mi++)
#pragma unroll
            for (int ni = 0; ni < 4; ni++)
                acc[mi][ni] = __builtin_amdgcn_mfma_f32_16x16x32_bf16(
                    af[mi].s, bfr[ni].s, acc[mi][ni], 0, 0, 0);
    }

#pragma unroll
    for (int mi = 0; mi < 4; mi++) {
#pragma unroll
        for (int ni = 0; ni < 4; ni++) {
            int col = n0 + wc * 64 + ni * 16 + lr;
            float bs = bias[col];
            int row0 = m0 + wr * 64 + mi * 16 + ls * 4;
            float v[4];
#pragma unroll
            for (int r = 0; r < 4; r++) {
                v[r] = acc[mi][ni][r] + bs;
                if (EPI == 2) v[r] = 0.5f * v[r] * (1.0f + erff(v[r] * 0.70710678118654752f));
            }
            if (EPI == 1) {
#pragma unroll
                for (int r = 0; r < 4; r++)
                    ((float*)Cout)[(size_t)(row0 + r) * N + col] = v[r];
            } else if (EPI == 3) {
                uint2 wv;
                wv.x = pack2(v[0], v[1]);
                wv.y = pack2(v[2], v[3]);
                *reinterpret_cast<uint2*>((u16*)Cout + (size_t)col * M + row0) = wv;
            } else {
#pragma unroll
                for (int r = 0; r < 4; r++)
                    ((u16*)Cout)[(size_t)(row0 + r) * N + col] = f2b(v[r]);
            }
        }
    }
}

// ---------------- residual add + LayerNorm (writes f32 + bf16) ----------------
__global__ __launch_bounds__(256) void resid_ln(const float* __restrict__ a,
                                                const float* __restrict__ res,
                                                const float* __restrict__ g,
                                                const float* __restrict__ be,
                                                float* __restrict__ of,
                                                u16* __restrict__ ob) {
    __shared__ float red[8];
    const int row = blockIdx.x;
    const int tid = threadIdx.x;
    const size_t base = (size_t)row * 768;
    float v[3];
    float s = 0.f;
#pragma unroll
    for (int i = 0; i < 3; i++) {
        int c = tid + i * 256;
        v[i] = a[base + c] + res[base + c];
        s += v[i];
    }
#pragma unroll
    for (int off = 32; off; off >>= 1) s += __shfl_down(s, off);
    if ((tid & 63) == 0) red[tid >> 6] = s;
    __syncthreads();
    float mean = (red[0] + red[1] + red[2] + red[3]) * (1.f / 768.f);
    float q = 0.f;
#pragma unroll
    for (int i = 0; i < 3; i++) {
        float d = v[i] - mean;
        q += d * d;
    }
#pragma unroll
    for (int off = 32; off; off >>= 1) q += __shfl_down(q, off);
    if ((tid & 63) == 0) red[4 + (tid >> 6)] = q;
    __syncthreads();
    float var = (red[4] + red[5] + red[6] + red[7]) * (1.f / 768.f);
    float inv = rsqrtf(var + 1e-12f);
#pragma unroll
    for (int i = 0; i < 3; i++) {
        int c = tid + i * 256;
        float y = (v[i] - mean) * inv * g[c] + be[c];
        of[base + c] = y;
        ob[base + c] = f2b(y);
    }
}

// ---------------- halo block attention (MFMA) ----------------
// grid: B*NBLK*H blocks, 256 threads (4 waves). Each block: one (b, n, h).
// K window [192][64] and P [128][104] share LDS region; V^T window [64][192].
__global__ __launch_bounds__(256) void attn_mfma(const u16* __restrict__ Q,
                                                 const u16* __restrict__ Kx,
                                                 const u16* __restrict__ Vt,
                                                 u16* __restrict__ Ctx) {
    __shared__ u16 sm0[128 * 104];  // P (padded stride 104); also K [192][64] swizzled
    __shared__ u16 sm1[64 * 192];   // V^T [64][192] swizzled
    u16* Ks = sm0;
    u16* Ps = sm0;
    u16* Vs = sm1;

    const int bid = blockIdx.x;
    const int h = bid % HH;
    const int n = (bid / HH) % NBLK;
    const int b = bid / (HH * NBLK);
    const int tid = threadIdx.x;
    const int lane = tid & 63, w = tid >> 6;
    const int lr = lane & 15, ls = lane >> 4;
    const int s0 = n * 128 - 32;

    // stage K window: rows j=0..191 (token s0+j, clamped; masked cols give P=0)
#pragma unroll
    for (int j = 0; j < 6; j++) {
        int r = (tid >> 3) + j * 32;
        int c = tid & 7;
        int s = min(max(s0 + r, 0), SS - 1);
        uint4 kv = *reinterpret_cast<const uint4*>(Kx + ((size_t)(b * SS + s)) * 768 + h * 64 + c * 8);
        int byteo = r * 128 + ((c * 16) ^ ((r & 7) << 4));
        *reinterpret_cast<uint4*>(Ks + (byteo >> 1)) = kv;
    }
    // stage V^T window: rows d=0..63, cols j=0..191 (clamped source; garbage ok, P=0)
#pragma unroll
    for (int j = 0; j < 6; j++) {
        int d = tid >> 2;
        int c = (tid & 3) + j * 4;
        int sv = min(max(s0 + c * 8, 0), SS - 8);
        uint4 vv = *reinterpret_cast<const uint4*>(Vt + ((size_t)(h * 64 + d)) * ROWS + b * SS + sv);
        int byteo = d * 384 + ((c * 16) ^ ((d & 7) << 4));
        *reinterpret_cast<uint4*>(Vs + (byteo >> 1)) = vv;
    }
    __syncthreads();

    // Q fragments direct from global: wave w owns query rows [w*32, w*32+32)
    const int qrow0 = b * SS + n * 128 + w * 32;
    U16x8 qf[2][2];
#pragma unroll
    for (int mi = 0; mi < 2; mi++)
#pragma unroll
        for (int ks = 0; ks < 2; ks++)
            qf[mi][ks].u = *reinterpret_cast<const uint4*>(
                Q + (size_t)(qrow0 + mi * 16 + lr) * 768 + h * 64 + ks * 32 + ls * 8);

    // QK^T: scores[2 mtiles][12 ntiles], C layout: col=lr (window j), row=ls*4+r
    f32x4 sc[2][12];
#pragma unroll
    for (int mi = 0; mi < 2; mi++)
#pragma unroll
        for (int jt = 0; jt < 12; jt++) sc[mi][jt] = (f32x4){0.f, 0.f, 0.f, 0.f};
#pragma unroll
    for (int jt = 0; jt < 12; jt++) {
        U16x8 kf[2];
#pragma unroll
        for (int ks = 0; ks < 2; ks++) {
            int r = jt * 16 + lr;
            int byteo = r * 128 + ((ks * 64 + ls * 16) ^ ((r & 7) << 4));
            kf[ks].u = *reinterpret_cast<const uint4*>(Ks + (byteo >> 1));
        }
#pragma unroll
        for (int mi = 0; mi < 2; mi++)
#pragma unroll
            for (int ks = 0; ks < 2; ks++)
                sc[mi][jt] = __builtin_amdgcn_mfma_f32_16x16x32_bf16(
                    qf[mi][ks].s, kf[ks].s, sc[mi][jt], 0, 0, 0);
    }

    // softmax (wave-parallel): scale, mask by column, row-max/sum via butterfly over lr
    const int lo = (n == 0) ? 32 : 0;
    const int hi = (n == NBLK - 1) ? 160 : 192;
    float mx[2][4], sm[2][4], inv[2][4];
#pragma unroll
    for (int mi = 0; mi < 2; mi++)
#pragma unroll
        for (int r = 0; r < 4; r++) { mx[mi][r] = -3.0e38f; sm[mi][r] = 0.f; }
#pragma unroll
    for (int jt = 0; jt < 12; jt++) {
        int col = jt * 16 + lr;
        bool valid = (col >= lo) && (col < hi);
#pragma unroll
        for (int mi = 0; mi < 2; mi++)
#pragma unroll
            for (int r = 0; r < 4; r++) {
                float v = valid ? sc[mi][jt][r] * 0.125f : -3.0e38f;
                sc[mi][jt][r] = v;
                mx[mi][r] = fmaxf(mx[mi][r], v);
            }
    }
#pragma unroll
    for (int o = 1; o <= 8; o <<= 1)
#pragma unroll
        for (int mi = 0; mi < 2; mi++)
#pragma unroll
            for (int r = 0; r < 4; r++)
                mx[mi][r] = fmaxf(mx[mi][r], __shfl_xor(mx[mi][r], o));
#pragma unroll
    for (int jt = 0; jt < 12; jt++)
#pragma unroll
        for (int mi = 0; mi < 2; mi++)
#pragma unroll
            for (int r = 0; r < 4; r++) {
                float p = __expf(sc[mi][jt][r] - mx[mi][r]);
                sc[mi][jt][r] = p;
                sm[mi][r] += p;
            }
#pragma unroll
    for (int o = 1; o <= 8; o <<= 1)
#pragma unroll
        for (int mi = 0; mi < 2; mi++)
#pragma unroll
            for (int r = 0; r < 4; r++)
                sm[mi][r] += __shfl_xor(sm[mi][r], o);
#pragma unroll
    for (int mi = 0; mi < 2; mi++)
#pragma unroll
        for (int r = 0; r < 4; r++) inv[mi][r] = 1.0f / sm[mi][r];

    // PV in two window-halves (P LDS reuses K region)
    f32x4 oacc[2][4];
#pragma unroll
    for (int mi = 0; mi < 2; mi++)
#pragma unroll
        for (int dt = 0; dt < 4; dt++) oacc[mi][dt] = (f32x4){0.f, 0.f, 0.f, 0.f};
    __syncthreads();  // all waves done reading Ks

#pragma unroll
    for (int ph = 0; ph < 2; ph++) {
#pragma unroll
        for (int jj = 0; jj < 6; jj++) {
            int jt = ph * 6 + jj;
#pragma unroll
            for (int mi = 0; mi < 2; mi++) {
                int row = w * 32 + mi * 16 + ls * 4;
#pragma unroll
                for (int r = 0; r < 4; r++)
                    Ps[(row + r) * 104 + jj * 16 + lr] = f2b(sc[mi][jt][r]);
            }
        }
        __syncthreads();
#pragma unroll
        for (int kk = 0; kk < 3; kk++) {
            U16x8 pf[2], vf[4];
#pragma unroll
            for (int mi = 0; mi < 2; mi++)
                pf[mi].u = *reinterpret_cast<const uint4*>(
                    Ps + (w * 32 + mi * 16 + lr) * 104 + kk * 32 + ls * 8);
#pragma unroll
            for (int dt = 0; dt < 4; dt++) {
                int rrow = dt * 16 + lr;
                int byteo = rrow * 384 + ((ph * 192 + kk * 64 + ls * 16) ^ ((rrow & 7) << 4));
                vf[dt].u = *reinterpret_cast<const uint4*>(Vs + (byteo >> 1));
            }
#pragma unroll
            for (int mi = 0; mi < 2; mi++)
#pragma unroll
                for (int dt = 0; dt < 4; dt++)
                    oacc[mi][dt] = __builtin_amdgcn_mfma_f32_16x16x32_bf16(
                        pf[mi].s, vf[dt].s, oacc[mi][dt], 0, 0, 0);
        }
        __syncthreads();
    }

    // epilogue: divide by rowsum, write ctx rows (C layout row=ls*4+r, col=lr)
#pragma unroll
    for (int mi = 0; mi < 2; mi++)
#pragma unroll
        for (int dt = 0; dt < 4; dt++)
#pragma unroll
            for (int r = 0; r < 4; r++) {
                float v = oacc[mi][dt][r] * inv[mi][r];
                Ctx[(size_t)(qrow0 + mi * 16 + ls * 4 + r) * 768 + h * 64 + dt * 16 + lr] = f2b(v);
            }
}

extern "C" void kernel_launch(void* const* d_in, const int* in_sizes, int n_in,
                              void* d_out, int out_size, void* d_ws, size_t ws_size,
                              hipStream_t stream) {
    (void)in_sizes; (void)n_in; (void)out_size; (void)ws_size;
    const float* x    = (const float*)d_in[0];
    const float* Wq   = (const float*)d_in[1];
    const float* bq   = (const float*)d_in[2];
    const float* Wk   = (const float*)d_in[3];
    const float* bk   = (const float*)d_in[4];
    const float* Wv   = (const float*)d_in[5];
    const float* bv   = (const float*)d_in[6];
    const float* Wo   = (const float*)d_in[7];
    const float* bo   = (const float*)d_in[8];
    const float* ln1g = (const float*)d_in[9];
    const float* ln1b = (const float*)d_in[10];
    const float* W1   = (const float*)d_in[11];
    const float* b1   = (const float*)d_in[12];
    const float* W2   = (const float*)d_in[13];
    const float* b2   = (const float*)d_in[14];
    const float* ln2g = (const float*)d_in[15];
    const float* ln2b = (const float*)d_in[16];
    float* out = (float*)d_out;

    char* ws = (char*)d_ws;
    size_t off = 0;
    auto alloc = [&](size_t bytes) -> char* {
        char* p = ws + off;
        off += (bytes + 255) & ~(size_t)255;
        return p;
    };
    u16* WqT = (u16*)alloc(2 * D2 * sizeof(u16));
    u16* WkT = (u16*)alloc(2 * D2 * sizeof(u16));
    u16* WvT = (u16*)alloc(2 * D2 * sizeof(u16));
    u16* WoT = (u16*)alloc(2 * D2 * sizeof(u16));
    u16* W1T = (u16*)alloc(2 * DI * sizeof(u16));
    u16* W2T = (u16*)alloc(2 * DI * sizeof(u16));
    u16* Xb   = (u16*)alloc(AD * sizeof(u16));
    u16* RegA = (u16*)alloc(4 * AD * sizeof(u16)); // Qb,Kb,Vt,Ctxb; reused as H1b
    float* AttnF = (float*)alloc(AD * sizeof(float));
    u16*   AttnB = (u16*)alloc(AD * sizeof(u16));
    float* H2f   = (float*)alloc(AD * sizeof(float));
    u16* Qb = RegA;
    u16* Kb = RegA + AD;
    u16* Vtb = RegA + 2 * AD;   // V^T layout: [feature][B*S]
    u16* Ctxb = RegA + 3 * AD;
    u16* H1b = RegA;

    {
        int nelem = ROWS * DD;
        cast_bf16<<<dim3(nelem / 4 / 256), dim3(256), 0, stream>>>(x, Xb, nelem);
    }
    for (int l = 0; l < 2; l++) {
        cast_transpose<<<dim3(24, 24), dim3(32, 8), 0, stream>>>(Wq + l * D2, WqT + l * D2, 768, 768);
        cast_transpose<<<dim3(24, 24), dim3(32, 8), 0, stream>>>(Wk + l * D2, WkT + l * D2, 768, 768);
        cast_transpose<<<dim3(24, 24), dim3(32, 8), 0, stream>>>(Wv + l * D2, WvT + l * D2, 768, 768);
        cast_transpose<<<dim3(24, 24), dim3(32, 8), 0, stream>>>(Wo + l * D2, WoT + l * D2, 768, 768);
        cast_transpose<<<dim3(96, 24), dim3(32, 8), 0, stream>>>(W1 + l * DI, W1T + l * DI, 768, 3072);
        cast_transpose<<<dim3(24, 96), dim3(32, 8), 0, stream>>>(W2 + l * DI, W2T + l * DI, 3072, 768);
    }

    const float* xres = x;
    for (int l = 0; l < 2; l++) {
        gemm_bf16<0><<<dim3(6, 128), 256, 0, stream>>>(Xb, WqT + l * D2, bq + l * 768, Qb, ROWS, 768, 768);
        gemm_bf16<0><<<dim3(6, 128), 256, 0, stream>>>(Xb, WkT + l * D2, bk + l * 768, Kb, ROWS, 768, 768);
        gemm_bf16<3><<<dim3(6, 128), 256, 0, stream>>>(Xb, WvT + l * D2, bv + l * 768, Vtb, ROWS, 768, 768);
        attn_mfma<<<dim3(BB * NBLK * HH), 256, 0, stream>>>(Qb, Kb, Vtb, Ctxb);
        gemm_bf16<1><<<dim3(6, 128), 256, 0, stream>>>(Ctxb, WoT + l * D2, bo + l * 768, H2f, ROWS, 768, 768);
        resid_ln<<<dim3(ROWS), 256, 0, stream>>>(H2f, xres, ln1g + l * 768, ln1b + l * 768, AttnF, AttnB);
        gemm_bf16<2><<<dim3(24, 128), 256, 0, stream>>>(AttnB, W1T + l * DI, b1 + l * 3072, H1b, ROWS, 3072, 768);
        gemm_bf16<1><<<dim3(6, 128), 256, 0, stream>>>(H1b, W2T + l * DI, b2 + l * 768, H2f, ROWS, 768, 3072);
        float* outl = out + (size_t)l * AD;
        resid_ln<<<dim3(ROWS), 256, 0, stream>>>(H2f, AttnF, ln2g + l * 768, ln2b + l * 768, outl, Xb);
        xres = outl;
    }
}